// Round 1
// baseline (172.190 us; speedup 1.0000x reference)
//
#include <hip/hip_runtime.h>
#include <hip/hip_bf16.h>
#include <math.h>

// ---------------------------------------------------------------------------
// GatedTinyMambaLayer: B=8, T=2048, DM=1024, DS=256
// out[b,t,:] = (h = s_corr*gate_in*gate_state) @ W_out^T ; plus h at t=T-1
// Key structural fact: s_prev is prev_state broadcast over T -> all
// s_prev-only terms are per-batch [8,256] precomputes.
// ---------------------------------------------------------------------------

typedef __attribute__((ext_vector_type(4)))  float f32x4;
typedef __attribute__((ext_vector_type(16))) float f32x16;
typedef __attribute__((ext_vector_type(8)))  short bf16x8;

#define DEV static __device__ __forceinline__

DEV float bf2f(short u) {
  union { float f; unsigned i; } v; v.i = ((unsigned)(unsigned short)u) << 16; return v.f;
}
DEV short f2bf(float f) {  // round-to-nearest-even
  union { float f; unsigned i; } v; v.f = f;
  unsigned x = v.i;
  return (short)((x + 0x7fffu + ((x >> 16) & 1u)) >> 16);
}
DEV float sigmoidf_(float x) { return 1.f / (1.f + expf(-x)); }

// ---- workspace layout (bytes) ---------------------------------------------
static const size_t OFF_Y    = 0;                   // bf16 [16384][768] = 24 MiB
static const size_t OFF_XBF  = 25165824;            // bf16 [16384][1024] = 32 MiB
static const size_t OFF_S    = OFF_XBF;             // bf16 [16384][256] (aliases xbf, dead then)
static const size_t OFF_G    = OFF_XBF + 8388608;   // bf16 [16384][256]
static const size_t OFF_WCAT = OFF_XBF + 33554432;  // bf16 [768][1024]
static const size_t OFF_WPP  = OFF_WCAT + 1572864;  // bf16 [256][256]  (W_pp[:, :256])
static const size_t OFF_WOUT = OFF_WPP + 131072;    // bf16 [1024][256]
static const size_t OFF_VEC  = OFF_WOUT + 524288;   // f32 [5][2048]: sdc,sws,spp,pstr,gst

// ---------------------------------------------------------------------------
// x f32 -> bf16
__global__ __launch_bounds__(256, 1) void cvt_x_k(const float* __restrict__ x,
                                                  short* __restrict__ xbf) {
  const size_t i = ((size_t)blockIdx.x * 256 + threadIdx.x) * 4;
  const float4 v = *(const float4*)(x + i);
  short4 o;
  o.x = f2bf(v.x); o.y = f2bf(v.y); o.z = f2bf(v.z); o.w = f2bf(v.w);
  *(short4*)(xbf + i) = o;
}

// ---------------------------------------------------------------------------
// weight prep: Wcat rows 0-255 = W_in+W_x, 256-511 = W_gx, 512-767 = W_dc[:, :1024]
__global__ __launch_bounds__(256, 1) void prep_w_k(const float* __restrict__ W_in,
                                                   const float* __restrict__ W_x,
                                                   const float* __restrict__ W_gx,
                                                   const float* __restrict__ W_dc,
                                                   const float* __restrict__ W_pp,
                                                   const float* __restrict__ W_out,
                                                   short* __restrict__ wcat,
                                                   short* __restrict__ wpp,
                                                   short* __restrict__ wout) {
  const int idx = (int)blockIdx.x * 256 + (int)threadIdx.x;
  const int N_WCAT = 768 * 1024, N_WPP = 256 * 256, N_WOUT = 1024 * 256;
  if (idx < N_WCAT) {
    const int r = idx >> 10, k = idx & 1023;
    float v;
    if (r < 256)      v = W_in[r * 1024 + k] + W_x[r * 1024 + k];
    else if (r < 512) v = W_gx[(r - 256) * 1024 + k];
    else              v = W_dc[(r - 512) * 1280 + k];
    wcat[idx] = f2bf(v);
  } else if (idx < N_WCAT + N_WPP) {
    const int j = idx - N_WCAT, o = j >> 8, k = j & 255;
    wpp[j] = f2bf(W_pp[o * 512 + k]);          // W_pp[:, :256] (s_pred part)
  } else {
    const int j = idx - N_WCAT - N_WPP, o = j >> 8, k = j & 255;
    wout[j] = f2bf(W_out[o * 256 + k]);
  }
}

// ---------------------------------------------------------------------------
// per-batch state vectors (K=256 GEMVs), f32
__global__ __launch_bounds__(256, 1) void state_k(const float* __restrict__ prev,
                                                  const float* __restrict__ Ws,
                                                  const float* __restrict__ Wdc,
                                                  const float* __restrict__ bdc,
                                                  const float* __restrict__ Wpp,
                                                  const float* __restrict__ bpp,
                                                  const float* __restrict__ Wpg,
                                                  const float* __restrict__ bpg,
                                                  const float* __restrict__ Wgs,
                                                  const float* __restrict__ bgs,
                                                  float* __restrict__ vecs) {
  __shared__ float sv[256];
  const int b = blockIdx.x, o = threadIdx.x;
  sv[o] = prev[b * 256 + o];
  __syncthreads();
  float adc = bdc[o], aws = 0.f, app = bpp[o], apg = bpg[o], ags = bgs[o];
  for (int k = 0; k < 256; ++k) {
    const float s = sv[k];
    adc += s * Wdc[o * 1280 + 1024 + k];   // W_dc[:, DM:]
    aws += s * Ws[o * 256 + k];
    app += s * Wpp[o * 512 + 256 + k];     // W_pp[:, 256:]
    apg += s * Wpg[o * 256 + k];
    ags += s * Wgs[o * 256 + k];
  }
  vecs[0 * 2048 + b * 256 + o] = adc;                 // sdc (incl b_dc)
  vecs[1 * 2048 + b * 256 + o] = 0.5f * aws;          // 0.5*s@W_s^T
  vecs[2 * 2048 + b * 256 + o] = app;                 // spp (incl b_pp)
  vecs[3 * 2048 + b * 256 + o] = sigmoidf_(apg);      // perturb_strength
  vecs[4 * 2048 + b * 256 + o] = sigmoidf_(ags);      // gate_state
}

// ---------------------------------------------------------------------------
// GEMM1: Y[16384][768] (bf16) = xbf @ Wcat^T. 128x128 tile, BK=32, dbuf padded LDS.
// Row stride 40 elems (80B = 5 granules, 5 coprime 8 -> conflict-free b128 frags).
__global__ __launch_bounds__(256, 1) void gemm1_k(const short* __restrict__ xbf,
                                                  const short* __restrict__ wcat,
                                                  short* __restrict__ Y) {
  __shared__ short As[2][128 * 40];
  __shared__ short Bs[2][128 * 40];
  const int tid = (int)threadIdx.x;
  const int l = tid & 63, w = tid >> 6, wr = w >> 1, wc = w & 1;
  const int m0 = ((int)blockIdx.x / 6) * 128;
  const int n0 = ((int)blockIdx.x % 6) * 128;
  const int srow = tid >> 1, sh = tid & 1;

  const short* ga = xbf + (size_t)(m0 + srow) * 1024 + sh * 16;
  const short* gb = wcat + (size_t)(n0 + srow) * 1024 + sh * 16;
  const int lw = srow * 40 + sh * 16;

  f32x4 acc[4][4];
#pragma unroll
  for (int mi = 0; mi < 4; ++mi)
#pragma unroll
    for (int ni = 0; ni < 4; ++ni)
#pragma unroll
      for (int r = 0; r < 4; ++r) acc[mi][ni][r] = 0.f;

  uint4 ra0 = *(const uint4*)(ga);
  uint4 ra1 = *(const uint4*)(ga + 8);
  uint4 rb0 = *(const uint4*)(gb);
  uint4 rb1 = *(const uint4*)(gb + 8);
  *(uint4*)&As[0][lw] = ra0; *(uint4*)&As[0][lw + 8] = ra1;
  *(uint4*)&Bs[0][lw] = rb0; *(uint4*)&Bs[0][lw + 8] = rb1;
  __syncthreads();

  const int arow = l & 15;
  const int ag = l >> 4;  // k-granule 0..3
#pragma unroll 1
  for (int t = 0; t < 32; ++t) {
    const int cur = t & 1;
    if (t < 31) {  // prefetch next tile into regs (latency hidden under MFMA)
      const short* pa = ga + (t + 1) * 32;
      const short* pb = gb + (t + 1) * 32;
      ra0 = *(const uint4*)(pa); ra1 = *(const uint4*)(pa + 8);
      rb0 = *(const uint4*)(pb); rb1 = *(const uint4*)(pb + 8);
    }
    bf16x8 af[4], bfr[4];
#pragma unroll
    for (int mi = 0; mi < 4; ++mi)
      af[mi] = *(const bf16x8*)&As[cur][(wr * 64 + mi * 16 + arow) * 40 + ag * 8];
#pragma unroll
    for (int ni = 0; ni < 4; ++ni)
      bfr[ni] = *(const bf16x8*)&Bs[cur][(wc * 64 + ni * 16 + arow) * 40 + ag * 8];
#pragma unroll
    for (int mi = 0; mi < 4; ++mi)
#pragma unroll
      for (int ni = 0; ni < 4; ++ni)
        acc[mi][ni] = __builtin_amdgcn_mfma_f32_16x16x32_bf16(af[mi], bfr[ni], acc[mi][ni], 0, 0, 0);
    if (t < 31) {
      *(uint4*)&As[cur ^ 1][lw] = ra0; *(uint4*)&As[cur ^ 1][lw + 8] = ra1;
      *(uint4*)&Bs[cur ^ 1][lw] = rb0; *(uint4*)&Bs[cur ^ 1][lw + 8] = rb1;
    }
    __syncthreads();  // single barrier per iter is sufficient with dbuf
  }
#pragma unroll
  for (int mi = 0; mi < 4; ++mi)
#pragma unroll
    for (int ni = 0; ni < 4; ++ni) {
      const int col = n0 + wc * 64 + ni * 16 + (l & 15);
#pragma unroll
      for (int r = 0; r < 4; ++r) {
        const int row = m0 + wr * 64 + mi * 16 + (l >> 4) * 4 + r;
        Y[(size_t)row * 768 + col] = f2bf(acc[mi][ni][r]);
      }
    }
}

// ---------------------------------------------------------------------------
// elementwise 1: Y -> s_pred (S, bf16), gate_in (G, bf16)
__global__ __launch_bounds__(256, 1) void elem1_k(const short* __restrict__ Y,
                                                  const float* __restrict__ prev,
                                                  const float* __restrict__ bgx,
                                                  const float* __restrict__ vecs,
                                                  short* __restrict__ S,
                                                  short* __restrict__ G) {
  const int t = (int)blockIdx.x * 256 + (int)threadIdx.x;  // 524288 total
  const int row = t >> 5, gi = t & 31, j0 = gi * 8;
  const int b = row >> 11;
  const short* yr = Y + (size_t)row * 768;
  const bf16x8 yix = *(const bf16x8*)(yr + j0);
  const bf16x8 ygx = *(const bf16x8*)(yr + 256 + j0);
  const bf16x8 ydc = *(const bf16x8*)(yr + 512 + j0);
  bf16x8 so, go;
#pragma unroll
  for (int j = 0; j < 8; ++j) {
    const int c = b * 256 + j0 + j;
    const float dcl = bf2f(ydc[j]) + vecs[0 * 2048 + c];
    const float dec = expf(-0.05f * sigmoidf_(dcl));
    const float sp = prev[c] * dec + bf2f(yix[j]) + vecs[1 * 2048 + c];
    const float g = sigmoidf_(bf2f(ygx[j]) + bgx[j0 + j]);
    so[j] = f2bf(sp); go[j] = f2bf(g);
  }
  *(bf16x8*)(S + (size_t)row * 256 + j0) = so;
  *(bf16x8*)(G + (size_t)row * 256 + j0) = go;
}

// ---------------------------------------------------------------------------
// fuse2: per 32-row block: GEMM2 (pv_lin = S@Wpp_s^T) -> elementwise -> h in LDS
//        -> GEMM3 (out = h@W_out^T). 8 waves, 32x32x16 MFMA, weights from L2.
// LDS row stride 264 elems (528B = 33 granules -> conflict-free frag reads).
__global__ __launch_bounds__(512, 1) void fuse2_k(const short* __restrict__ S,
                                                  const short* __restrict__ G,
                                                  const short* __restrict__ Wpp,
                                                  const short* __restrict__ Wout,
                                                  const float* __restrict__ vecs,
                                                  float* __restrict__ out) {
  __shared__ short Sl[32 * 264];
  __shared__ short Hl[32 * 264];
  const int tid = (int)threadIdx.x;
  const int l = tid & 63, w = tid >> 6;
  const int r0 = (int)blockIdx.x * 32;
  const int b = r0 >> 11;
  {  // stage S tile [32][256] -> padded LDS
    const int srow = tid >> 4;
    const int g2 = (tid & 15) * 2;
    const uint4* ps = (const uint4*)(S + (size_t)(r0 + srow) * 256 + g2 * 8);
    const uint4 s0 = ps[0], s1 = ps[1];
    *(uint4*)&Sl[srow * 264 + g2 * 8] = s0;
    *(uint4*)&Sl[srow * 264 + g2 * 8 + 8] = s1;
  }
  __syncthreads();
  const int arow = l & 31, ahi = l >> 5;
  const int col = w * 32 + arow;
  // GEMM2: K=256
  f32x16 accP;
#pragma unroll
  for (int r = 0; r < 16; ++r) accP[r] = 0.f;
#pragma unroll
  for (int ks = 0; ks < 16; ++ks) {
    const bf16x8 a = *(const bf16x8*)&Sl[arow * 264 + ks * 16 + ahi * 8];
    const bf16x8 bb = *(const bf16x8*)(Wpp + (size_t)col * 256 + ks * 16 + ahi * 8);
    accP = __builtin_amdgcn_mfma_f32_32x32x16_bf16(a, bb, accP, 0, 0, 0);
  }
  const float* spp = vecs + 2 * 2048 + b * 256;
  const float* pstr = vecs + 3 * 2048 + b * 256;
  const float* gst = vecs + 4 * 2048 + b * 256;
#pragma unroll
  for (int r = 0; r < 16; ++r) {
    const int rowt = (r & 3) + 8 * (r >> 2) + 4 * ahi;
    const int R = r0 + rowt;
    const float pv = tanhf(accP[r] + spp[col]);
    const float sp = bf2f(Sl[rowt * 264 + col]);
    const float sc = sp + pstr[col] * pv;
    const float giv = bf2f(G[(size_t)R * 256 + col]);
    const float h = sc * giv * gst[col];
    Hl[rowt * 264 + col] = f2bf(h);
    if ((R & 2047) == 2047) out[16777216 + b * 256 + col] = h;  // h_last (f32)
  }
  __syncthreads();
  // GEMM3: N=1024, K=256
  f32x16 acc3[4];
#pragma unroll
  for (int q = 0; q < 4; ++q)
#pragma unroll
    for (int r = 0; r < 16; ++r) acc3[q][r] = 0.f;
#pragma unroll
  for (int ks = 0; ks < 16; ++ks) {
    const bf16x8 a = *(const bf16x8*)&Hl[arow * 264 + ks * 16 + ahi * 8];
#pragma unroll
    for (int q = 0; q < 4; ++q) {
      const int oc = (w * 4 + q) * 32 + arow;
      const bf16x8 bb = *(const bf16x8*)(Wout + (size_t)oc * 256 + ks * 16 + ahi * 8);
      acc3[q] = __builtin_amdgcn_mfma_f32_32x32x16_bf16(a, bb, acc3[q], 0, 0, 0);
    }
  }
#pragma unroll
  for (int q = 0; q < 4; ++q) {
    const int oc = (w * 4 + q) * 32 + arow;
#pragma unroll
    for (int r = 0; r < 16; ++r) {
      const int rowt = (r & 3) + 8 * (r >> 2) + 4 * ahi;
      out[(size_t)(r0 + rowt) * 1024 + oc] = acc3[q][r];
    }
  }
}

// ---------------------------------------------------------------------------
extern "C" void kernel_launch(void* const* d_in, const int* in_sizes, int n_in,
                              void* d_out, int out_size, void* d_ws, size_t ws_size,
                              hipStream_t stream) {
  (void)in_sizes; (void)n_in; (void)out_size; (void)ws_size;
  const float* x      = (const float*)d_in[0];
  const float* prev   = (const float*)d_in[1];
  const float* W_in   = (const float*)d_in[2];
  const float* W_x    = (const float*)d_in[3];
  const float* W_s    = (const float*)d_in[4];
  const float* W_out  = (const float*)d_in[5];
  const float* W_gx   = (const float*)d_in[6];
  const float* b_gx   = (const float*)d_in[7];
  const float* W_gs   = (const float*)d_in[8];
  const float* b_gs   = (const float*)d_in[9];
  const float* W_dc   = (const float*)d_in[10];
  const float* b_dc   = (const float*)d_in[11];
  const float* W_pp   = (const float*)d_in[12];
  const float* b_pp   = (const float*)d_in[13];
  const float* W_pg   = (const float*)d_in[14];
  const float* b_pg   = (const float*)d_in[15];

  char* ws = (char*)d_ws;
  short* Y    = (short*)(ws + OFF_Y);
  short* xbf  = (short*)(ws + OFF_XBF);
  short* S    = (short*)(ws + OFF_S);
  short* G    = (short*)(ws + OFF_G);
  short* wcat = (short*)(ws + OFF_WCAT);
  short* wpp  = (short*)(ws + OFF_WPP);
  short* wout = (short*)(ws + OFF_WOUT);
  float* vecs = (float*)(ws + OFF_VEC);
  float* out  = (float*)d_out;

  cvt_x_k<<<16384, 256, 0, stream>>>(x, xbf);
  prep_w_k<<<4352, 256, 0, stream>>>(W_in, W_x, W_gx, W_dc, W_pp, W_out, wcat, wpp, wout);
  state_k<<<8, 256, 0, stream>>>(prev, W_s, W_dc, b_dc, W_pp, b_pp, W_pg, b_pg, W_gs, b_gs, vecs);
  gemm1_k<<<768, 256, 0, stream>>>(xbf, wcat, Y);
  elem1_k<<<2048, 256, 0, stream>>>(Y, prev, b_gx, vecs, S, G);
  fuse2_k<<<512, 512, 0, stream>>>(S, G, wpp, wout, vecs, out);
}

// Round 2
// 155.999 us; speedup vs baseline: 1.1038x; 1.1038x over previous
//
#include <hip/hip_runtime.h>
#include <hip/hip_bf16.h>
#include <math.h>

// ---------------------------------------------------------------------------
// GatedTinyMambaLayer: B=8, T=2048, DM=1024, DS=256
// s_prev = broadcast(prev_state) -> all s_prev-only terms are per-batch
// [8,256] precomputes. Heavy work = 3 GEMMs, all m97-style (128x128 tile,
// BK=32, global_load_lds width 16, dbuf LDS, 1 barrier/K-step).
// ---------------------------------------------------------------------------

typedef __attribute__((ext_vector_type(4)))  float f32x4;
typedef __attribute__((ext_vector_type(8)))  short bf16x8;

#define DEV static __device__ __forceinline__

DEV float bf2f(short u) {
  union { float f; unsigned i; } v; v.i = ((unsigned)(unsigned short)u) << 16; return v.f;
}
DEV short f2bf(float f) {  // round-to-nearest-even
  union { float f; unsigned i; } v; v.f = f;
  unsigned x = v.i;
  return (short)((x + 0x7fffu + ((x >> 16) & 1u)) >> 16);
}
DEV float sigmoidf_(float x) { return 1.f / (1.f + expf(-x)); }

DEV void gl16(const short* g, short* l) {
  __builtin_amdgcn_global_load_lds(
      (const __attribute__((address_space(1))) void*)(g),
      (__attribute__((address_space(3))) void*)(l), 16, 0, 0);
}

// stage one 128x32 A-subtile + 128x32 B-subtile into linear LDS [128][32]
// (each wave: 2 x 1KB segments per matrix; LDS base wave-uniform, global per-lane)
DEV void stage_tile(const short* gA, const short* gB, short* As, short* Bs,
                    int lda, int ldb, int w, int lane) {
  const int rsub = lane >> 2, kc = (lane & 3) * 8;
#pragma unroll
  for (int j = 0; j < 2; ++j) {
    const int seg = w * 2 + j;           // 0..7, 16 rows each
    const int r = seg * 16 + rsub;
    gl16(gA + (size_t)r * lda + kc, As + seg * 512);
    gl16(gB + (size_t)r * ldb + kc, Bs + seg * 512);
  }
}

DEV void kstep(const short* Asb, const short* Bsb, int wr, int wc, int arow, int ag,
               f32x4 (&acc)[4][4]) {
  bf16x8 af[4], bfv[4];
#pragma unroll
  for (int mi = 0; mi < 4; ++mi)
    af[mi] = *(const bf16x8*)(Asb + (wr * 64 + mi * 16 + arow) * 32 + ag * 8);
#pragma unroll
  for (int ni = 0; ni < 4; ++ni)
    bfv[ni] = *(const bf16x8*)(Bsb + (wc * 64 + ni * 16 + arow) * 32 + ag * 8);
#pragma unroll
  for (int mi = 0; mi < 4; ++mi)
#pragma unroll
    for (int ni = 0; ni < 4; ++ni)
      acc[mi][ni] = __builtin_amdgcn_mfma_f32_16x16x32_bf16(af[mi], bfv[ni], acc[mi][ni], 0, 0, 0);
}

// ---- workspace layout (bytes) ---------------------------------------------
static const size_t OFF_Y    = 0;                   // bf16 [16384][768] = 24 MiB; H aliases after elem1
static const size_t OFF_XBF  = 25165824;            // bf16 [16384][1024] = 32 MiB
static const size_t OFF_S    = OFF_XBF;             // bf16 [16384][256] (aliases xbf, dead then)
static const size_t OFF_G    = OFF_XBF + 8388608;   // bf16 [16384][256]
static const size_t OFF_WCAT = OFF_XBF + 33554432;  // bf16 [768][1024]
static const size_t OFF_WPP  = OFF_WCAT + 1572864;  // bf16 [256][256]  (W_pp[:, :256])
static const size_t OFF_WOUT = OFF_WPP + 131072;    // bf16 [1024][256]
static const size_t OFF_VEC  = OFF_WOUT + 524288;   // f32 [5][2048]: sdc,sws,spp,pstr,gst

// ---------------------------------------------------------------------------
__global__ __launch_bounds__(256, 1) void cvt_x_k(const float* __restrict__ x,
                                                  short* __restrict__ xbf) {
  const size_t i = ((size_t)blockIdx.x * 256 + threadIdx.x) * 4;
  const float4 v = *(const float4*)(x + i);
  short4 o;
  o.x = f2bf(v.x); o.y = f2bf(v.y); o.z = f2bf(v.z); o.w = f2bf(v.w);
  *(short4*)(xbf + i) = o;
}

// ---------------------------------------------------------------------------
__global__ __launch_bounds__(256, 1) void prep_w_k(const float* __restrict__ W_in,
                                                   const float* __restrict__ W_x,
                                                   const float* __restrict__ W_gx,
                                                   const float* __restrict__ W_dc,
                                                   const float* __restrict__ W_pp,
                                                   const float* __restrict__ W_out,
                                                   short* __restrict__ wcat,
                                                   short* __restrict__ wpp,
                                                   short* __restrict__ wout) {
  const int idx = (int)blockIdx.x * 256 + (int)threadIdx.x;
  const int N_WCAT = 768 * 1024, N_WPP = 256 * 256;
  if (idx < N_WCAT) {
    const int r = idx >> 10, k = idx & 1023;
    float v;
    if (r < 256)      v = W_in[r * 1024 + k] + W_x[r * 1024 + k];
    else if (r < 512) v = W_gx[(r - 256) * 1024 + k];
    else              v = W_dc[(r - 512) * 1280 + k];
    wcat[idx] = f2bf(v);
  } else if (idx < N_WCAT + N_WPP) {
    const int j = idx - N_WCAT, o = j >> 8, k = j & 255;
    wpp[j] = f2bf(W_pp[o * 512 + k]);          // W_pp[:, :256] (s_pred part)
  } else {
    const int j = idx - N_WCAT - N_WPP, o = j >> 8, k = j & 255;
    wout[j] = f2bf(W_out[o * 256 + k]);
  }
}

// ---------------------------------------------------------------------------
__global__ __launch_bounds__(256, 1) void state_k(const float* __restrict__ prev,
                                                  const float* __restrict__ Ws,
                                                  const float* __restrict__ Wdc,
                                                  const float* __restrict__ bdc,
                                                  const float* __restrict__ Wpp,
                                                  const float* __restrict__ bpp,
                                                  const float* __restrict__ Wpg,
                                                  const float* __restrict__ bpg,
                                                  const float* __restrict__ Wgs,
                                                  const float* __restrict__ bgs,
                                                  float* __restrict__ vecs) {
  __shared__ float sv[256];
  const int b = blockIdx.x, o = threadIdx.x;
  sv[o] = prev[b * 256 + o];
  __syncthreads();
  float adc = bdc[o], aws = 0.f, app = bpp[o], apg = bpg[o], ags = bgs[o];
  for (int k = 0; k < 256; ++k) {
    const float s = sv[k];
    adc += s * Wdc[o * 1280 + 1024 + k];   // W_dc[:, DM:]
    aws += s * Ws[o * 256 + k];
    app += s * Wpp[o * 512 + 256 + k];     // W_pp[:, 256:]
    apg += s * Wpg[o * 256 + k];
    ags += s * Wgs[o * 256 + k];
  }
  vecs[0 * 2048 + b * 256 + o] = adc;                 // sdc (incl b_dc)
  vecs[1 * 2048 + b * 256 + o] = 0.5f * aws;          // 0.5*s@W_s^T
  vecs[2 * 2048 + b * 256 + o] = app;                 // spp (incl b_pp)
  vecs[3 * 2048 + b * 256 + o] = sigmoidf_(apg);      // perturb_strength
  vecs[4 * 2048 + b * 256 + o] = sigmoidf_(ags);      // gate_state
}

// ---------------------------------------------------------------------------
// GEMM1: Y[16384][768] bf16 = xbf @ wcat^T.  K=1024 -> 32 k-steps.
__global__ __launch_bounds__(256) void gemm1_k(const short* __restrict__ A,
                                               const short* __restrict__ Bm,
                                               short* __restrict__ Y) {
  __shared__ short As[2][4096];
  __shared__ short Bs[2][4096];
  const int tid = (int)threadIdx.x, lane = tid & 63, w = tid >> 6;
  const int wr = w >> 1, wc = w & 1;
  int bid = (int)blockIdx.x;
  bid = (bid & 7) * 96 + (bid >> 3);           // XCD swizzle (768 % 8 == 0)
  const int m0 = (bid / 6) * 128, n0 = (bid % 6) * 128;
  const short* gA = A + (size_t)m0 * 1024;
  const short* gB = Bm + (size_t)n0 * 1024;

  f32x4 acc[4][4];
#pragma unroll
  for (int mi = 0; mi < 4; ++mi)
#pragma unroll
    for (int ni = 0; ni < 4; ++ni)
#pragma unroll
      for (int r = 0; r < 4; ++r) acc[mi][ni][r] = 0.f;

  stage_tile(gA, gB, As[0], Bs[0], 1024, 1024, w, lane);
  __syncthreads();
  const int arow = lane & 15, ag = lane >> 4;
#pragma unroll 1
  for (int t = 0; t < 32; ++t) {
    if (t < 31)
      stage_tile(gA + (t + 1) * 32, gB + (t + 1) * 32,
                 As[(t + 1) & 1], Bs[(t + 1) & 1], 1024, 1024, w, lane);
    kstep(As[t & 1], Bs[t & 1], wr, wc, arow, ag, acc);
    __syncthreads();
  }
#pragma unroll
  for (int mi = 0; mi < 4; ++mi)
#pragma unroll
    for (int ni = 0; ni < 4; ++ni) {
      const int col = n0 + wc * 64 + ni * 16 + (lane & 15);
#pragma unroll
      for (int r = 0; r < 4; ++r) {
        const int row = m0 + wr * 64 + mi * 16 + (lane >> 4) * 4 + r;
        Y[(size_t)row * 768 + col] = f2bf(acc[mi][ni][r]);
      }
    }
}

// ---------------------------------------------------------------------------
// elementwise 1: Y -> s_pred (S, bf16), gate_in (G, bf16)
__global__ __launch_bounds__(256, 1) void elem1_k(const short* __restrict__ Y,
                                                  const float* __restrict__ prev,
                                                  const float* __restrict__ bgx,
                                                  const float* __restrict__ vecs,
                                                  short* __restrict__ S,
                                                  short* __restrict__ G) {
  const int t = (int)blockIdx.x * 256 + (int)threadIdx.x;  // 524288 total
  const int row = t >> 5, gi = t & 31, j0 = gi * 8;
  const int b = row >> 11;
  const short* yr = Y + (size_t)row * 768;
  const bf16x8 yix = *(const bf16x8*)(yr + j0);
  const bf16x8 ygx = *(const bf16x8*)(yr + 256 + j0);
  const bf16x8 ydc = *(const bf16x8*)(yr + 512 + j0);
  bf16x8 so, go;
#pragma unroll
  for (int j = 0; j < 8; ++j) {
    const int c = b * 256 + j0 + j;
    const float dcl = bf2f(ydc[j]) + vecs[0 * 2048 + c];
    const float dec = expf(-0.05f * sigmoidf_(dcl));
    const float sp = prev[c] * dec + bf2f(yix[j]) + vecs[1 * 2048 + c];
    const float g = sigmoidf_(bf2f(ygx[j]) + bgx[j0 + j]);
    so[j] = f2bf(sp); go[j] = f2bf(g);
  }
  *(bf16x8*)(S + (size_t)row * 256 + j0) = so;
  *(bf16x8*)(G + (size_t)row * 256 + j0) = go;
}

// ---------------------------------------------------------------------------
// GEMM2 + elementwise: P = S @ wpp^T; h = (S + pstr*tanh(P+spp)) * G * gst
// writes H bf16 [16384][256] (+ h_last f32). K=256 -> 8 k-steps. N=256 -> 2 n-tiles.
__global__ __launch_bounds__(256) void gemm2h_k(const short* __restrict__ S,
                                                const short* __restrict__ G,
                                                const short* __restrict__ Wpp,
                                                const float* __restrict__ vecs,
                                                short* __restrict__ H,
                                                float* __restrict__ out) {
  __shared__ short As[2][4096];
  __shared__ short Bs[2][4096];
  const int tid = (int)threadIdx.x, lane = tid & 63, w = tid >> 6;
  const int wr = w >> 1, wc = w & 1;
  int bid = (int)blockIdx.x;
  bid = (bid & 7) * 32 + (bid >> 3);           // 256 % 8 == 0
  const int m0 = (bid >> 1) * 128, n0 = (bid & 1) * 128;
  const int b = m0 >> 11;
  const short* gA = S + (size_t)m0 * 256;
  const short* gB = Wpp + (size_t)n0 * 256;

  f32x4 acc[4][4];
#pragma unroll
  for (int mi = 0; mi < 4; ++mi)
#pragma unroll
    for (int ni = 0; ni < 4; ++ni)
#pragma unroll
      for (int r = 0; r < 4; ++r) acc[mi][ni][r] = 0.f;

  stage_tile(gA, gB, As[0], Bs[0], 256, 256, w, lane);
  __syncthreads();
  const int arow = lane & 15, ag = lane >> 4;
#pragma unroll 1
  for (int t = 0; t < 8; ++t) {
    if (t < 7)
      stage_tile(gA + (t + 1) * 32, gB + (t + 1) * 32,
                 As[(t + 1) & 1], Bs[(t + 1) & 1], 256, 256, w, lane);
    kstep(As[t & 1], Bs[t & 1], wr, wc, arow, ag, acc);
    __syncthreads();
  }
#pragma unroll
  for (int mi = 0; mi < 4; ++mi)
#pragma unroll
    for (int ni = 0; ni < 4; ++ni) {
      const int col = n0 + wc * 64 + ni * 16 + (lane & 15);
      const float spp  = vecs[2 * 2048 + b * 256 + col];
      const float pstr = vecs[3 * 2048 + b * 256 + col];
      const float gst  = vecs[4 * 2048 + b * 256 + col];
#pragma unroll
      for (int r = 0; r < 4; ++r) {
        const int row = m0 + wr * 64 + mi * 16 + (lane >> 4) * 4 + r;
        const float pv = tanhf(acc[mi][ni][r] + spp);
        const float sp = bf2f(S[(size_t)row * 256 + col]);
        const float h = (sp + pstr * pv) * bf2f(G[(size_t)row * 256 + col]) * gst;
        H[(size_t)row * 256 + col] = f2bf(h);
        if ((row & 2047) == 2047) out[16777216 + b * 256 + col] = h;
      }
    }
}

// ---------------------------------------------------------------------------
// GEMM3: out[16384][1024] f32 = H @ wout^T. K=256 -> 8 k-steps.
__global__ __launch_bounds__(256) void gemm3_k(const short* __restrict__ H,
                                               const short* __restrict__ Wout,
                                               float* __restrict__ out) {
  __shared__ short As[2][4096];
  __shared__ short Bs[2][4096];
  const int tid = (int)threadIdx.x, lane = tid & 63, w = tid >> 6;
  const int wr = w >> 1, wc = w & 1;
  int bid = (int)blockIdx.x;
  bid = (bid & 7) * 128 + (bid >> 3);          // 1024 % 8 == 0
  const int m0 = (bid >> 3) * 128, n0 = (bid & 7) * 128;
  const short* gA = H + (size_t)m0 * 256;
  const short* gB = Wout + (size_t)n0 * 256;

  f32x4 acc[4][4];
#pragma unroll
  for (int mi = 0; mi < 4; ++mi)
#pragma unroll
    for (int ni = 0; ni < 4; ++ni)
#pragma unroll
      for (int r = 0; r < 4; ++r) acc[mi][ni][r] = 0.f;

  stage_tile(gA, gB, As[0], Bs[0], 256, 256, w, lane);
  __syncthreads();
  const int arow = lane & 15, ag = lane >> 4;
#pragma unroll 1
  for (int t = 0; t < 8; ++t) {
    if (t < 7)
      stage_tile(gA + (t + 1) * 32, gB + (t + 1) * 32,
                 As[(t + 1) & 1], Bs[(t + 1) & 1], 256, 256, w, lane);
    kstep(As[t & 1], Bs[t & 1], wr, wc, arow, ag, acc);
    __syncthreads();
  }
#pragma unroll
  for (int mi = 0; mi < 4; ++mi)
#pragma unroll
    for (int ni = 0; ni < 4; ++ni) {
      const int col = n0 + wc * 64 + ni * 16 + (lane & 15);
#pragma unroll
      for (int r = 0; r < 4; ++r) {
        const int row = m0 + wr * 64 + mi * 16 + (lane >> 4) * 4 + r;
        out[(size_t)row * 1024 + col] = acc[mi][ni][r];
      }
    }
}

// ---------------------------------------------------------------------------
extern "C" void kernel_launch(void* const* d_in, const int* in_sizes, int n_in,
                              void* d_out, int out_size, void* d_ws, size_t ws_size,
                              hipStream_t stream) {
  (void)in_sizes; (void)n_in; (void)out_size; (void)ws_size;
  const float* x      = (const float*)d_in[0];
  const float* prev   = (const float*)d_in[1];
  const float* W_in   = (const float*)d_in[2];
  const float* W_x    = (const float*)d_in[3];
  const float* W_s    = (const float*)d_in[4];
  const float* W_out  = (const float*)d_in[5];
  const float* W_gx   = (const float*)d_in[6];
  const float* b_gx   = (const float*)d_in[7];
  const float* W_gs   = (const float*)d_in[8];
  const float* b_gs   = (const float*)d_in[9];
  const float* W_dc   = (const float*)d_in[10];
  const float* b_dc   = (const float*)d_in[11];
  const float* W_pp   = (const float*)d_in[12];
  const float* b_pp   = (const float*)d_in[13];
  const float* W_pg   = (const float*)d_in[14];
  const float* b_pg   = (const float*)d_in[15];

  char* ws = (char*)d_ws;
  short* Y    = (short*)(ws + OFF_Y);
  short* H    = (short*)(ws + OFF_Y);     // aliases Y (dead after elem1)
  short* xbf  = (short*)(ws + OFF_XBF);
  short* S    = (short*)(ws + OFF_S);     // aliases xbf (dead after gemm1)
  short* G    = (short*)(ws + OFF_G);
  short* wcat = (short*)(ws + OFF_WCAT);
  short* wpp  = (short*)(ws + OFF_WPP);
  short* wout = (short*)(ws + OFF_WOUT);
  float* vecs = (float*)(ws + OFF_VEC);
  float* out  = (float*)d_out;

  cvt_x_k<<<16384, 256, 0, stream>>>(x, xbf);
  prep_w_k<<<4352, 256, 0, stream>>>(W_in, W_x, W_gx, W_dc, W_pp, W_out, wcat, wpp, wout);
  state_k<<<8, 256, 0, stream>>>(prev, W_s, W_dc, b_dc, W_pp, b_pp, W_pg, b_pg, W_gs, b_gs, vecs);
  gemm1_k<<<768, 256, 0, stream>>>(xbf, wcat, Y);
  elem1_k<<<2048, 256, 0, stream>>>(Y, prev, b_gx, vecs, S, G);
  gemm2h_k<<<256, 256, 0, stream>>>(S, G, wpp, vecs, H, out);
  gemm3_k<<<1024, 256, 0, stream>>>(H, wout, out);
}

// Round 3
// 122.082 us; speedup vs baseline: 1.4104x; 1.2778x over previous
//
#include <hip/hip_runtime.h>
#include <hip/hip_bf16.h>
#include <math.h>

// ---------------------------------------------------------------------------
// GatedTinyMambaLayer: B=8, T=2048, DM=1024, DS=256
// s_prev = broadcast(prev_state) -> all s_prev-only terms are per-batch
// [8,256] precomputes. Heavy work = 3 GEMMs, all m97-style (128x128 tile,
// BK=32, global_load_lds width 16, dbuf LDS, 1 barrier/K-step).
// ---------------------------------------------------------------------------

typedef __attribute__((ext_vector_type(4)))  float f32x4;
typedef __attribute__((ext_vector_type(8)))  short bf16x8;

#define DEV static __device__ __forceinline__

DEV float bf2f(short u) {
  union { float f; unsigned i; } v; v.i = ((unsigned)(unsigned short)u) << 16; return v.f;
}
DEV short f2bf(float f) {  // round-to-nearest-even
  union { float f; unsigned i; } v; v.f = f;
  unsigned x = v.i;
  return (short)((x + 0x7fffu + ((x >> 16) & 1u)) >> 16);
}
DEV float sigmoidf_(float x) { return 1.f / (1.f + expf(-x)); }

DEV void gl16(const short* g, short* l) {
  __builtin_amdgcn_global_load_lds(
      (const __attribute__((address_space(1))) void*)(g),
      (__attribute__((address_space(3))) void*)(l), 16, 0, 0);
}

// stage one 128x32 A-subtile + 128x32 B-subtile into linear LDS [128][32]
DEV void stage_tile(const short* gA, const short* gB, short* As, short* Bs,
                    int lda, int ldb, int w, int lane) {
  const int rsub = lane >> 2, kc = (lane & 3) * 8;
#pragma unroll
  for (int j = 0; j < 2; ++j) {
    const int seg = w * 2 + j;           // 0..7, 16 rows each
    const int r = seg * 16 + rsub;
    gl16(gA + (size_t)r * lda + kc, As + seg * 512);
    gl16(gB + (size_t)r * ldb + kc, Bs + seg * 512);
  }
}

DEV void kstep(const short* Asb, const short* Bsb, int wr, int wc, int arow, int ag,
               f32x4 (&acc)[4][4]) {
  bf16x8 af[4], bfv[4];
#pragma unroll
  for (int mi = 0; mi < 4; ++mi)
    af[mi] = *(const bf16x8*)(Asb + (wr * 64 + mi * 16 + arow) * 32 + ag * 8);
#pragma unroll
  for (int ni = 0; ni < 4; ++ni)
    bfv[ni] = *(const bf16x8*)(Bsb + (wc * 64 + ni * 16 + arow) * 32 + ag * 8);
#pragma unroll
  for (int mi = 0; mi < 4; ++mi)
#pragma unroll
    for (int ni = 0; ni < 4; ++ni)
      acc[mi][ni] = __builtin_amdgcn_mfma_f32_16x16x32_bf16(af[mi], bfv[ni], acc[mi][ni], 0, 0, 0);
}

// ---- workspace layout (bytes) ---------------------------------------------
static const size_t OFF_Y    = 0;                   // bf16 [16384][768] = 24 MiB; H aliases after elem1
static const size_t OFF_XBF  = 25165824;            // bf16 [16384][1024] = 32 MiB
static const size_t OFF_S    = OFF_XBF;             // bf16 [16384][256] (aliases xbf, dead then)
static const size_t OFF_G    = OFF_XBF + 8388608;   // bf16 [16384][256]
static const size_t OFF_WCAT = OFF_XBF + 33554432;  // bf16 [768][1024]
static const size_t OFF_WPP  = OFF_WCAT + 1572864;  // bf16 [256][256]  (W_pp[:, :256])
static const size_t OFF_WOUT = OFF_WPP + 131072;    // bf16 [1024][256]
static const size_t OFF_VEC  = OFF_WOUT + 524288;   // f32 [5][2048]: sdc,sws,spp,pstr,gst

// ---------------------------------------------------------------------------
__global__ __launch_bounds__(256, 1) void cvt_x_k(const float* __restrict__ x,
                                                  short* __restrict__ xbf) {
  const size_t i = ((size_t)blockIdx.x * 256 + threadIdx.x) * 4;
  const float4 v = *(const float4*)(x + i);
  short4 o;
  o.x = f2bf(v.x); o.y = f2bf(v.y); o.z = f2bf(v.z); o.w = f2bf(v.w);
  *(short4*)(xbf + i) = o;
}

// ---------------------------------------------------------------------------
__global__ __launch_bounds__(256, 1) void prep_w_k(const float* __restrict__ W_in,
                                                   const float* __restrict__ W_x,
                                                   const float* __restrict__ W_gx,
                                                   const float* __restrict__ W_dc,
                                                   const float* __restrict__ W_pp,
                                                   const float* __restrict__ W_out,
                                                   short* __restrict__ wcat,
                                                   short* __restrict__ wpp,
                                                   short* __restrict__ wout) {
  const int idx = (int)blockIdx.x * 256 + (int)threadIdx.x;
  const int N_WCAT = 768 * 1024, N_WPP = 256 * 256;
  if (idx < N_WCAT) {
    const int r = idx >> 10, k = idx & 1023;
    float v;
    if (r < 256)      v = W_in[r * 1024 + k] + W_x[r * 1024 + k];
    else if (r < 512) v = W_gx[(r - 256) * 1024 + k];
    else              v = W_dc[(r - 512) * 1280 + k];
    wcat[idx] = f2bf(v);
  } else if (idx < N_WCAT + N_WPP) {
    const int j = idx - N_WCAT, o = j >> 8, k = j & 255;
    wpp[j] = f2bf(W_pp[o * 512 + k]);          // W_pp[:, :256] (s_pred part)
  } else {
    const int j = idx - N_WCAT - N_WPP, o = j >> 8, k = j & 255;
    wout[j] = f2bf(W_out[o * 256 + k]);
  }
}

// ---------------------------------------------------------------------------
// per-batch state GEMVs, coalesced direction: lanes span K (float4 each),
// one weight-row read is contiguous 1KB; shfl_xor butterfly reduce.
// grid = 8 batches x 5 matrices x 4 output-quads = 160 blocks.
__global__ __launch_bounds__(256, 1) void state_k(const float* __restrict__ prev,
                                                  const float* __restrict__ Ws,
                                                  const float* __restrict__ Wdc,
                                                  const float* __restrict__ bdc,
                                                  const float* __restrict__ Wpp,
                                                  const float* __restrict__ bpp,
                                                  const float* __restrict__ Wpg,
                                                  const float* __restrict__ bpg,
                                                  const float* __restrict__ Wgs,
                                                  const float* __restrict__ bgs,
                                                  float* __restrict__ vecs) {
  const int bid = (int)blockIdx.x;
  const int b = bid / 20, rem = bid % 20, m = rem >> 2, oq = rem & 3;
  const int tid = (int)threadIdx.x, lane = tid & 63, w = tid >> 6;
  const float4 sv = *(const float4*)(prev + b * 256 + lane * 4);
  const float* Wb; const float* bias; int stride, off;
  if (m == 0)      { Wb = Wdc; stride = 1280; off = 1024; bias = bdc; }
  else if (m == 1) { Wb = Ws;  stride = 256;  off = 0;    bias = nullptr; }
  else if (m == 2) { Wb = Wpp; stride = 512;  off = 256;  bias = bpp; }
  else if (m == 3) { Wb = Wpg; stride = 256;  off = 0;    bias = bpg; }
  else             { Wb = Wgs; stride = 256;  off = 0;    bias = bgs; }
  const int o0 = oq * 64 + w * 16;
#pragma unroll 4
  for (int i = 0; i < 16; ++i) {
    const int o = o0 + i;
    const float4 wv = *(const float4*)(Wb + (size_t)o * stride + off + lane * 4);
    float p = wv.x * sv.x + wv.y * sv.y + wv.z * sv.z + wv.w * sv.w;
#pragma unroll
    for (int d = 32; d >= 1; d >>= 1) p += __shfl_xor(p, d, 64);
    if (lane == 0) {
      float r = (m == 1) ? 0.5f * p : p + bias[o];
      if (m >= 3) r = sigmoidf_(r);
      vecs[m * 2048 + b * 256 + o] = r;
    }
  }
}

// ---------------------------------------------------------------------------
// GEMM1: Y[16384][768] bf16 = xbf @ wcat^T.  K=1024 -> 32 k-steps.
__global__ __launch_bounds__(256) void gemm1_k(const short* __restrict__ A,
                                               const short* __restrict__ Bm,
                                               short* __restrict__ Y) {
  __shared__ short As[2][4096];
  __shared__ short Bs[2][4096];
  const int tid = (int)threadIdx.x, lane = tid & 63, w = tid >> 6;
  const int wr = w >> 1, wc = w & 1;
  int bid = (int)blockIdx.x;
  bid = (bid & 7) * 96 + (bid >> 3);           // XCD swizzle (768 % 8 == 0)
  const int m0 = (bid / 6) * 128, n0 = (bid % 6) * 128;
  const short* gA = A + (size_t)m0 * 1024;
  const short* gB = Bm + (size_t)n0 * 1024;

  f32x4 acc[4][4];
#pragma unroll
  for (int mi = 0; mi < 4; ++mi)
#pragma unroll
    for (int ni = 0; ni < 4; ++ni)
#pragma unroll
      for (int r = 0; r < 4; ++r) acc[mi][ni][r] = 0.f;

  stage_tile(gA, gB, As[0], Bs[0], 1024, 1024, w, lane);
  __syncthreads();
  const int arow = lane & 15, ag = lane >> 4;
#pragma unroll 1
  for (int t = 0; t < 32; ++t) {
    if (t < 31)
      stage_tile(gA + (t + 1) * 32, gB + (t + 1) * 32,
                 As[(t + 1) & 1], Bs[(t + 1) & 1], 1024, 1024, w, lane);
    kstep(As[t & 1], Bs[t & 1], wr, wc, arow, ag, acc);
    __syncthreads();
  }
#pragma unroll
  for (int mi = 0; mi < 4; ++mi)
#pragma unroll
    for (int ni = 0; ni < 4; ++ni) {
      const int col = n0 + wc * 64 + ni * 16 + (lane & 15);
#pragma unroll
      for (int r = 0; r < 4; ++r) {
        const int row = m0 + wr * 64 + mi * 16 + (lane >> 4) * 4 + r;
        Y[(size_t)row * 768 + col] = f2bf(acc[mi][ni][r]);
      }
    }
}

// ---------------------------------------------------------------------------
// elementwise 1: Y -> s_pred (S, bf16), gate_in (G, bf16)
__global__ __launch_bounds__(256, 1) void elem1_k(const short* __restrict__ Y,
                                                  const float* __restrict__ prev,
                                                  const float* __restrict__ bgx,
                                                  const float* __restrict__ vecs,
                                                  short* __restrict__ S,
                                                  short* __restrict__ G) {
  const int t = (int)blockIdx.x * 256 + (int)threadIdx.x;  // 524288 total
  const int row = t >> 5, gi = t & 31, j0 = gi * 8;
  const int b = row >> 11;
  const short* yr = Y + (size_t)row * 768;
  const bf16x8 yix = *(const bf16x8*)(yr + j0);
  const bf16x8 ygx = *(const bf16x8*)(yr + 256 + j0);
  const bf16x8 ydc = *(const bf16x8*)(yr + 512 + j0);
  bf16x8 so, go;
#pragma unroll
  for (int j = 0; j < 8; ++j) {
    const int c = b * 256 + j0 + j;
    const float dcl = bf2f(ydc[j]) + vecs[0 * 2048 + c];
    const float dec = expf(-0.05f * sigmoidf_(dcl));
    const float sp = prev[c] * dec + bf2f(yix[j]) + vecs[1 * 2048 + c];
    const float g = sigmoidf_(bf2f(ygx[j]) + bgx[j0 + j]);
    so[j] = f2bf(sp); go[j] = f2bf(g);
  }
  *(bf16x8*)(S + (size_t)row * 256 + j0) = so;
  *(bf16x8*)(G + (size_t)row * 256 + j0) = go;
}

// ---------------------------------------------------------------------------
// GEMM2 + elementwise: P = S @ wpp^T; h = (S + pstr*tanh(P+spp)) * G * gst
__global__ __launch_bounds__(256) void gemm2h_k(const short* __restrict__ S,
                                                const short* __restrict__ G,
                                                const short* __restrict__ Wpp,
                                                const float* __restrict__ vecs,
                                                short* __restrict__ H,
                                                float* __restrict__ out) {
  __shared__ short As[2][4096];
  __shared__ short Bs[2][4096];
  const int tid = (int)threadIdx.x, lane = tid & 63, w = tid >> 6;
  const int wr = w >> 1, wc = w & 1;
  int bid = (int)blockIdx.x;
  bid = (bid & 7) * 32 + (bid >> 3);           // 256 % 8 == 0
  const int m0 = (bid >> 1) * 128, n0 = (bid & 1) * 128;
  const int b = m0 >> 11;
  const short* gA = S + (size_t)m0 * 256;
  const short* gB = Wpp + (size_t)n0 * 256;

  f32x4 acc[4][4];
#pragma unroll
  for (int mi = 0; mi < 4; ++mi)
#pragma unroll
    for (int ni = 0; ni < 4; ++ni)
#pragma unroll
      for (int r = 0; r < 4; ++r) acc[mi][ni][r] = 0.f;

  stage_tile(gA, gB, As[0], Bs[0], 256, 256, w, lane);
  __syncthreads();
  const int arow = lane & 15, ag = lane >> 4;
#pragma unroll 1
  for (int t = 0; t < 8; ++t) {
    if (t < 7)
      stage_tile(gA + (t + 1) * 32, gB + (t + 1) * 32,
                 As[(t + 1) & 1], Bs[(t + 1) & 1], 256, 256, w, lane);
    kstep(As[t & 1], Bs[t & 1], wr, wc, arow, ag, acc);
    __syncthreads();
  }
#pragma unroll
  for (int mi = 0; mi < 4; ++mi)
#pragma unroll
    for (int ni = 0; ni < 4; ++ni) {
      const int col = n0 + wc * 64 + ni * 16 + (lane & 15);
      const float spp  = vecs[2 * 2048 + b * 256 + col];
      const float pstr = vecs[3 * 2048 + b * 256 + col];
      const float gst  = vecs[4 * 2048 + b * 256 + col];
#pragma unroll
      for (int r = 0; r < 4; ++r) {
        const int row = m0 + wr * 64 + mi * 16 + (lane >> 4) * 4 + r;
        const float pv = tanhf(acc[mi][ni][r] + spp);
        const float sp = bf2f(S[(size_t)row * 256 + col]);
        const float h = (sp + pstr * pv) * bf2f(G[(size_t)row * 256 + col]) * gst;
        H[(size_t)row * 256 + col] = f2bf(h);
        if ((row & 2047) == 2047) out[16777216 + b * 256 + col] = h;
      }
    }
}

// ---------------------------------------------------------------------------
// GEMM3: out[16384][1024] f32 = H @ wout^T. K=256 -> 8 k-steps.
__global__ __launch_bounds__(256) void gemm3_k(const short* __restrict__ H,
                                               const short* __restrict__ Wout,
                                               float* __restrict__ out) {
  __shared__ short As[2][4096];
  __shared__ short Bs[2][4096];
  const int tid = (int)threadIdx.x, lane = tid & 63, w = tid >> 6;
  const int wr = w >> 1, wc = w & 1;
  int bid = (int)blockIdx.x;
  bid = (bid & 7) * 128 + (bid >> 3);          // 1024 % 8 == 0
  const int m0 = (bid >> 3) * 128, n0 = (bid & 7) * 128;
  const short* gA = H + (size_t)m0 * 256;
  const short* gB = Wout + (size_t)n0 * 256;

  f32x4 acc[4][4];
#pragma unroll
  for (int mi = 0; mi < 4; ++mi)
#pragma unroll
    for (int ni = 0; ni < 4; ++ni)
#pragma unroll
      for (int r = 0; r < 4; ++r) acc[mi][ni][r] = 0.f;

  stage_tile(gA, gB, As[0], Bs[0], 256, 256, w, lane);
  __syncthreads();
  const int arow = lane & 15, ag = lane >> 4;
#pragma unroll 1
  for (int t = 0; t < 8; ++t) {
    if (t < 7)
      stage_tile(gA + (t + 1) * 32, gB + (t + 1) * 32,
                 As[(t + 1) & 1], Bs[(t + 1) & 1], 256, 256, w, lane);
    kstep(As[t & 1], Bs[t & 1], wr, wc, arow, ag, acc);
    __syncthreads();
  }
#pragma unroll
  for (int mi = 0; mi < 4; ++mi)
#pragma unroll
    for (int ni = 0; ni < 4; ++ni) {
      const int col = n0 + wc * 64 + ni * 16 + (lane & 15);
#pragma unroll
      for (int r = 0; r < 4; ++r) {
        const int row = m0 + wr * 64 + mi * 16 + (lane >> 4) * 4 + r;
        out[(size_t)row * 1024 + col] = acc[mi][ni][r];
      }
    }
}

// ---------------------------------------------------------------------------
extern "C" void kernel_launch(void* const* d_in, const int* in_sizes, int n_in,
                              void* d_out, int out_size, void* d_ws, size_t ws_size,
                              hipStream_t stream) {
  (void)in_sizes; (void)n_in; (void)out_size; (void)ws_size;
  const float* x      = (const float*)d_in[0];
  const float* prev   = (const float*)d_in[1];
  const float* W_in   = (const float*)d_in[2];
  const float* W_x    = (const float*)d_in[3];
  const float* W_s    = (const float*)d_in[4];
  const float* W_out  = (const float*)d_in[5];
  const float* W_gx   = (const float*)d_in[6];
  const float* b_gx   = (const float*)d_in[7];
  const float* W_gs   = (const float*)d_in[8];
  const float* b_gs   = (const float*)d_in[9];
  const float* W_dc   = (const float*)d_in[10];
  const float* b_dc   = (const float*)d_in[11];
  const float* W_pp   = (const float*)d_in[12];
  const float* b_pp   = (const float*)d_in[13];
  const float* W_pg   = (const float*)d_in[14];
  const float* b_pg   = (const float*)d_in[15];

  char* ws = (char*)d_ws;
  short* Y    = (short*)(ws + OFF_Y);
  short* H    = (short*)(ws + OFF_Y);     // aliases Y (dead after elem1)
  short* xbf  = (short*)(ws + OFF_XBF);
  short* S    = (short*)(ws + OFF_S);     // aliases xbf (dead after gemm1)
  short* G    = (short*)(ws + OFF_G);
  short* wcat = (short*)(ws + OFF_WCAT);
  short* wpp  = (short*)(ws + OFF_WPP);
  short* wout = (short*)(ws + OFF_WOUT);
  float* vecs = (float*)(ws + OFF_VEC);
  float* out  = (float*)d_out;

  cvt_x_k<<<16384, 256, 0, stream>>>(x, xbf);
  prep_w_k<<<4352, 256, 0, stream>>>(W_in, W_x, W_gx, W_dc, W_pp, W_out, wcat, wpp, wout);
  state_k<<<160, 256, 0, stream>>>(prev, W_s, W_dc, b_dc, W_pp, b_pp, W_pg, b_pg, W_gs, b_gs, vecs);
  gemm1_k<<<768, 256, 0, stream>>>(xbf, wcat, Y);
  elem1_k<<<2048, 256, 0, stream>>>(Y, prev, b_gx, vecs, S, G);
  gemm2h_k<<<256, 256, 0, stream>>>(S, G, wpp, vecs, H, out);
  gemm3_k<<<1024, 256, 0, stream>>>(H, wout, out);
}

// Round 4
// 117.661 us; speedup vs baseline: 1.4634x; 1.0376x over previous
//
#include <hip/hip_runtime.h>
#include <hip/hip_bf16.h>
#include <math.h>

// ---------------------------------------------------------------------------
// GatedTinyMambaLayer: B=8, T=2048, DM=1024, DS=256
// s_prev = broadcast(prev_state) -> all s_prev-only terms are per-batch
// [8,256] precomputes. Heavy work = 3 GEMMs (m97-style: 128x128 tile, BK=32,
// global_load_lds width 16 for bf16 operands, dbuf LDS, 1 barrier/K-step).
// gemm1 fuses x f32->bf16 conversion into A-staging (reg-staged, T14 split).
// ---------------------------------------------------------------------------

typedef __attribute__((ext_vector_type(4)))  float f32x4;
typedef __attribute__((ext_vector_type(8)))  short bf16x8;

#define DEV static __device__ __forceinline__

DEV float bf2f(short u) {
  union { float f; unsigned i; } v; v.i = ((unsigned)(unsigned short)u) << 16; return v.f;
}
DEV short f2bf(float f) {  // round-to-nearest-even
  union { float f; unsigned i; } v; v.f = f;
  unsigned x = v.i;
  return (short)((x + 0x7fffu + ((x >> 16) & 1u)) >> 16);
}
DEV unsigned pk_bf16(float lo, float hi) {  // -> v_cvt_pk_bf16_f32
  __hip_bfloat162 h = __float22bfloat162_rn(make_float2(lo, hi));
  return *(unsigned*)&h;
}
DEV float sigmoidf_(float x) { return 1.f / (1.f + expf(-x)); }

DEV void gl16(const short* g, short* l) {
  __builtin_amdgcn_global_load_lds(
      (const __attribute__((address_space(1))) void*)(g),
      (__attribute__((address_space(3))) void*)(l), 16, 0, 0);
}

// stage one 128x32 bf16 subtile pair into linear LDS [128][32] via gload_lds
DEV void stage_tile(const short* gA, const short* gB, short* As, short* Bs,
                    int lda, int ldb, int w, int lane) {
  const int rsub = lane >> 2, kc = (lane & 3) * 8;
#pragma unroll
  for (int j = 0; j < 2; ++j) {
    const int seg = w * 2 + j;           // 0..7, 16 rows each
    const int r = seg * 16 + rsub;
    gl16(gA + (size_t)r * lda + kc, As + seg * 512);
    gl16(gB + (size_t)r * ldb + kc, Bs + seg * 512);
  }
}

DEV void kstep(const short* Asb, const short* Bsb, int wr, int wc, int arow, int ag,
               f32x4 (&acc)[4][4]) {
  bf16x8 af[4], bfv[4];
#pragma unroll
  for (int mi = 0; mi < 4; ++mi)
    af[mi] = *(const bf16x8*)(Asb + (wr * 64 + mi * 16 + arow) * 32 + ag * 8);
#pragma unroll
  for (int ni = 0; ni < 4; ++ni)
    bfv[ni] = *(const bf16x8*)(Bsb + (wc * 64 + ni * 16 + arow) * 32 + ag * 8);
#pragma unroll
  for (int mi = 0; mi < 4; ++mi)
#pragma unroll
    for (int ni = 0; ni < 4; ++ni)
      acc[mi][ni] = __builtin_amdgcn_mfma_f32_16x16x32_bf16(af[mi], bfv[ni], acc[mi][ni], 0, 0, 0);
}

// ---- workspace layout (bytes) ---------------------------------------------
static const size_t OFF_Y    = 0;                   // bf16 [16384][768] = 24 MiB; H aliases after elem1
static const size_t OFF_S    = 25165824;            // bf16 [16384][256]
static const size_t OFF_G    = OFF_S + 8388608;     // bf16 [16384][256]
static const size_t OFF_WCAT = OFF_S + 33554432;    // bf16 [768][1024]
static const size_t OFF_WPP  = OFF_WCAT + 1572864;  // bf16 [256][256]  (W_pp[:, :256])
static const size_t OFF_WOUT = OFF_WPP + 131072;    // bf16 [1024][256]
static const size_t OFF_VEC  = OFF_WOUT + 524288;   // f32 [5][2048]: sdc,sws,spp,pstr,gst

// ---------------------------------------------------------------------------
__global__ __launch_bounds__(256, 1) void prep_w_k(const float* __restrict__ W_in,
                                                   const float* __restrict__ W_x,
                                                   const float* __restrict__ W_gx,
                                                   const float* __restrict__ W_dc,
                                                   const float* __restrict__ W_pp,
                                                   const float* __restrict__ W_out,
                                                   short* __restrict__ wcat,
                                                   short* __restrict__ wpp,
                                                   short* __restrict__ wout) {
  const int idx = (int)blockIdx.x * 256 + (int)threadIdx.x;
  const int N_WCAT = 768 * 1024, N_WPP = 256 * 256;
  if (idx < N_WCAT) {
    const int r = idx >> 10, k = idx & 1023;
    float v;
    if (r < 256)      v = W_in[r * 1024 + k] + W_x[r * 1024 + k];
    else if (r < 512) v = W_gx[(r - 256) * 1024 + k];
    else              v = W_dc[(r - 512) * 1280 + k];
    wcat[idx] = f2bf(v);
  } else if (idx < N_WCAT + N_WPP) {
    const int j = idx - N_WCAT, o = j >> 8, k = j & 255;
    wpp[j] = f2bf(W_pp[o * 512 + k]);          // W_pp[:, :256] (s_pred part)
  } else {
    const int j = idx - N_WCAT - N_WPP, o = j >> 8, k = j & 255;
    wout[j] = f2bf(W_out[o * 256 + k]);
  }
}

// ---------------------------------------------------------------------------
// per-batch state GEMVs, coalesced: lanes span K (float4 each), butterfly reduce.
__global__ __launch_bounds__(256, 1) void state_k(const float* __restrict__ prev,
                                                  const float* __restrict__ Ws,
                                                  const float* __restrict__ Wdc,
                                                  const float* __restrict__ bdc,
                                                  const float* __restrict__ Wpp,
                                                  const float* __restrict__ bpp,
                                                  const float* __restrict__ Wpg,
                                                  const float* __restrict__ bpg,
                                                  const float* __restrict__ Wgs,
                                                  const float* __restrict__ bgs,
                                                  float* __restrict__ vecs) {
  const int bid = (int)blockIdx.x;
  const int b = bid / 20, rem = bid % 20, m = rem >> 2, oq = rem & 3;
  const int tid = (int)threadIdx.x, lane = tid & 63, w = tid >> 6;
  const float4 sv = *(const float4*)(prev + b * 256 + lane * 4);
  const float* Wb; const float* bias; int stride, off;
  if (m == 0)      { Wb = Wdc; stride = 1280; off = 1024; bias = bdc; }
  else if (m == 1) { Wb = Ws;  stride = 256;  off = 0;    bias = nullptr; }
  else if (m == 2) { Wb = Wpp; stride = 512;  off = 256;  bias = bpp; }
  else if (m == 3) { Wb = Wpg; stride = 256;  off = 0;    bias = bpg; }
  else             { Wb = Wgs; stride = 256;  off = 0;    bias = bgs; }
  const int o0 = oq * 64 + w * 16;
#pragma unroll 4
  for (int i = 0; i < 16; ++i) {
    const int o = o0 + i;
    const float4 wv = *(const float4*)(Wb + (size_t)o * stride + off + lane * 4);
    float p = wv.x * sv.x + wv.y * sv.y + wv.z * sv.z + wv.w * sv.w;
#pragma unroll
    for (int d = 32; d >= 1; d >>= 1) p += __shfl_xor(p, d, 64);
    if (lane == 0) {
      float r = (m == 1) ? 0.5f * p : p + bias[o];
      if (m >= 3) r = sigmoidf_(r);
      vecs[m * 2048 + b * 256 + o] = r;
    }
  }
}

// ---------------------------------------------------------------------------
// GEMM1: Y[16384][768] bf16 = x @ wcat^T.  K=1024 -> 32 k-steps.
// A (x, f32) is reg-staged with fused f32->bf16 conversion: global loads for
// tile t+1 issued BEFORE the MFMA cluster, cvt+ds_write after (T14 split).
// B (wcat, bf16) staged via global_load_lds width-16.
__global__ __launch_bounds__(256) void gemm1_k(const float* __restrict__ X,
                                               const short* __restrict__ Bm,
                                               short* __restrict__ Y) {
  __shared__ short As[2][4096];
  __shared__ short Bs[2][4096];
  const int tid = (int)threadIdx.x, lane = tid & 63, w = tid >> 6;
  const int wr = w >> 1, wc = w & 1;
  int bid = (int)blockIdx.x;
  bid = (bid & 7) * 96 + (bid >> 3);           // XCD swizzle (768 % 8 == 0)
  const int m0 = (bid / 6) * 128, n0 = (bid % 6) * 128;
  const short* gB = Bm + (size_t)n0 * 1024;

  const int rsub = lane >> 2, kc = (lane & 3) * 8;
  const float* gX0 = X + (size_t)(m0 + w * 32 + rsub) * 1024 + kc;       // j=0 row
  const float* gX1 = X + (size_t)(m0 + w * 32 + 16 + rsub) * 1024 + kc;  // j=1 row
  short* lA0 = (short*)As;  // + buf*4096 + (w*2+j)*512 + lane*8 (shorts)

  f32x4 acc[4][4];
#pragma unroll
  for (int mi = 0; mi < 4; ++mi)
#pragma unroll
    for (int ni = 0; ni < 4; ++ni)
#pragma unroll
      for (int r = 0; r < 4; ++r) acc[mi][ni][r] = 0.f;

  float4 ra[2][2];
  // prologue: tile 0
  ra[0][0] = *(const float4*)(gX0);     ra[0][1] = *(const float4*)(gX0 + 4);
  ra[1][0] = *(const float4*)(gX1);     ra[1][1] = *(const float4*)(gX1 + 4);
  {
    const int rB = (w * 2) * 16 + rsub;
    gl16(gB + (size_t)rB * 1024 + kc, Bs[0] + (w * 2) * 512);
    gl16(gB + (size_t)(rB + 16) * 1024 + kc, Bs[0] + (w * 2 + 1) * 512);
  }
#pragma unroll
  for (int j = 0; j < 2; ++j) {
    uint4 pk;
    pk.x = pk_bf16(ra[j][0].x, ra[j][0].y); pk.y = pk_bf16(ra[j][0].z, ra[j][0].w);
    pk.z = pk_bf16(ra[j][1].x, ra[j][1].y); pk.w = pk_bf16(ra[j][1].z, ra[j][1].w);
    *(uint4*)(lA0 + (w * 2 + j) * 512 + lane * 8) = pk;
  }
  __syncthreads();

  const int arow = lane & 15, ag = lane >> 4;
#pragma unroll 1
  for (int t = 0; t < 32; ++t) {
    const int nxt = (t + 1) & 1;
    if (t < 31) {  // issue next-tile loads early: latency hides under MFMA
      ra[0][0] = *(const float4*)(gX0 + (t + 1) * 32);
      ra[0][1] = *(const float4*)(gX0 + (t + 1) * 32 + 4);
      ra[1][0] = *(const float4*)(gX1 + (t + 1) * 32);
      ra[1][1] = *(const float4*)(gX1 + (t + 1) * 32 + 4);
      const int rB = (w * 2) * 16 + rsub;
      gl16(gB + (size_t)rB * 1024 + (t + 1) * 32 + kc, Bs[nxt] + (w * 2) * 512);
      gl16(gB + (size_t)(rB + 16) * 1024 + (t + 1) * 32 + kc, Bs[nxt] + (w * 2 + 1) * 512);
    }
    kstep(As[t & 1], Bs[t & 1], wr, wc, arow, ag, acc);
    if (t < 31) {
#pragma unroll
      for (int j = 0; j < 2; ++j) {
        uint4 pk;
        pk.x = pk_bf16(ra[j][0].x, ra[j][0].y); pk.y = pk_bf16(ra[j][0].z, ra[j][0].w);
        pk.z = pk_bf16(ra[j][1].x, ra[j][1].y); pk.w = pk_bf16(ra[j][1].z, ra[j][1].w);
        *(uint4*)(lA0 + nxt * 4096 + (w * 2 + j) * 512 + lane * 8) = pk;
      }
    }
    __syncthreads();
  }
#pragma unroll
  for (int mi = 0; mi < 4; ++mi)
#pragma unroll
    for (int ni = 0; ni < 4; ++ni) {
      const int col = n0 + wc * 64 + ni * 16 + (lane & 15);
#pragma unroll
      for (int r = 0; r < 4; ++r) {
        const int row = m0 + wr * 64 + mi * 16 + (lane >> 4) * 4 + r;
        Y[(size_t)row * 768 + col] = f2bf(acc[mi][ni][r]);
      }
    }
}

// ---------------------------------------------------------------------------
// elementwise 1: Y -> s_pred (S, bf16), gate_in (G, bf16)
__global__ __launch_bounds__(256, 1) void elem1_k(const short* __restrict__ Y,
                                                  const float* __restrict__ prev,
                                                  const float* __restrict__ bgx,
                                                  const float* __restrict__ vecs,
                                                  short* __restrict__ S,
                                                  short* __restrict__ G) {
  const int t = (int)blockIdx.x * 256 + (int)threadIdx.x;  // 524288 total
  const int row = t >> 5, gi = t & 31, j0 = gi * 8;
  const int b = row >> 11;
  const short* yr = Y + (size_t)row * 768;
  const bf16x8 yix = *(const bf16x8*)(yr + j0);
  const bf16x8 ygx = *(const bf16x8*)(yr + 256 + j0);
  const bf16x8 ydc = *(const bf16x8*)(yr + 512 + j0);
  bf16x8 so, go;
#pragma unroll
  for (int j = 0; j < 8; ++j) {
    const int c = b * 256 + j0 + j;
    const float dcl = bf2f(ydc[j]) + vecs[0 * 2048 + c];
    const float dec = expf(-0.05f * sigmoidf_(dcl));
    const float sp = prev[c] * dec + bf2f(yix[j]) + vecs[1 * 2048 + c];
    const float g = sigmoidf_(bf2f(ygx[j]) + bgx[j0 + j]);
    so[j] = f2bf(sp); go[j] = f2bf(g);
  }
  *(bf16x8*)(S + (size_t)row * 256 + j0) = so;
  *(bf16x8*)(G + (size_t)row * 256 + j0) = go;
}

// ---------------------------------------------------------------------------
// GEMM2 + elementwise: P = S @ wpp^T; h = (S + pstr*tanh(P+spp)) * G * gst
__global__ __launch_bounds__(256) void gemm2h_k(const short* __restrict__ S,
                                                const short* __restrict__ G,
                                                const short* __restrict__ Wpp,
                                                const float* __restrict__ vecs,
                                                short* __restrict__ H,
                                                float* __restrict__ out) {
  __shared__ short As[2][4096];
  __shared__ short Bs[2][4096];
  const int tid = (int)threadIdx.x, lane = tid & 63, w = tid >> 6;
  const int wr = w >> 1, wc = w & 1;
  int bid = (int)blockIdx.x;
  bid = (bid & 7) * 32 + (bid >> 3);           // 256 % 8 == 0
  const int m0 = (bid >> 1) * 128, n0 = (bid & 1) * 128;
  const int b = m0 >> 11;
  const short* gA = S + (size_t)m0 * 256;
  const short* gB = Wpp + (size_t)n0 * 256;

  f32x4 acc[4][4];
#pragma unroll
  for (int mi = 0; mi < 4; ++mi)
#pragma unroll
    for (int ni = 0; ni < 4; ++ni)
#pragma unroll
      for (int r = 0; r < 4; ++r) acc[mi][ni][r] = 0.f;

  stage_tile(gA, gB, As[0], Bs[0], 256, 256, w, lane);
  __syncthreads();
  const int arow = lane & 15, ag = lane >> 4;
#pragma unroll 1
  for (int t = 0; t < 8; ++t) {
    if (t < 7)
      stage_tile(gA + (t + 1) * 32, gB + (t + 1) * 32,
                 As[(t + 1) & 1], Bs[(t + 1) & 1], 256, 256, w, lane);
    kstep(As[t & 1], Bs[t & 1], wr, wc, arow, ag, acc);
    __syncthreads();
  }
#pragma unroll
  for (int mi = 0; mi < 4; ++mi)
#pragma unroll
    for (int ni = 0; ni < 4; ++ni) {
      const int col = n0 + wc * 64 + ni * 16 + (lane & 15);
      const float spp  = vecs[2 * 2048 + b * 256 + col];
      const float pstr = vecs[3 * 2048 + b * 256 + col];
      const float gst  = vecs[4 * 2048 + b * 256 + col];
#pragma unroll
      for (int r = 0; r < 4; ++r) {
        const int row = m0 + wr * 64 + mi * 16 + (lane >> 4) * 4 + r;
        const float pv = tanhf(acc[mi][ni][r] + spp);
        const float sp = bf2f(S[(size_t)row * 256 + col]);
        const float h = (sp + pstr * pv) * bf2f(G[(size_t)row * 256 + col]) * gst;
        H[(size_t)row * 256 + col] = f2bf(h);
        if ((row & 2047) == 2047) out[16777216 + b * 256 + col] = h;
      }
    }
}

// ---------------------------------------------------------------------------
// GEMM3: out[16384][1024] f32 = H @ wout^T. K=256 -> 8 k-steps.
__global__ __launch_bounds__(256) void gemm3_k(const short* __restrict__ H,
                                               const short* __restrict__ Wout,
                                               float* __restrict__ out) {
  __shared__ short As[2][4096];
  __shared__ short Bs[2][4096];
  const int tid = (int)threadIdx.x, lane = tid & 63, w = tid >> 6;
  const int wr = w >> 1, wc = w & 1;
  int bid = (int)blockIdx.x;
  bid = (bid & 7) * 128 + (bid >> 3);          // 1024 % 8 == 0
  const int m0 = (bid >> 3) * 128, n0 = (bid & 7) * 128;
  const short* gA = H + (size_t)m0 * 256;
  const short* gB = Wout + (size_t)n0 * 256;

  f32x4 acc[4][4];
#pragma unroll
  for (int mi = 0; mi < 4; ++mi)
#pragma unroll
    for (int ni = 0; ni < 4; ++ni)
#pragma unroll
      for (int r = 0; r < 4; ++r) acc[mi][ni][r] = 0.f;

  stage_tile(gA, gB, As[0], Bs[0], 256, 256, w, lane);
  __syncthreads();
  const int arow = lane & 15, ag = lane >> 4;
#pragma unroll 1
  for (int t = 0; t < 8; ++t) {
    if (t < 7)
      stage_tile(gA + (t + 1) * 32, gB + (t + 1) * 32,
                 As[(t + 1) & 1], Bs[(t + 1) & 1], 256, 256, w, lane);
    kstep(As[t & 1], Bs[t & 1], wr, wc, arow, ag, acc);
    __syncthreads();
  }
#pragma unroll
  for (int mi = 0; mi < 4; ++mi)
#pragma unroll
    for (int ni = 0; ni < 4; ++ni) {
      const int col = n0 + wc * 64 + ni * 16 + (lane & 15);
#pragma unroll
      for (int r = 0; r < 4; ++r) {
        const int row = m0 + wr * 64 + mi * 16 + (lane >> 4) * 4 + r;
        out[(size_t)row * 1024 + col] = acc[mi][ni][r];
      }
    }
}

// ---------------------------------------------------------------------------
extern "C" void kernel_launch(void* const* d_in, const int* in_sizes, int n_in,
                              void* d_out, int out_size, void* d_ws, size_t ws_size,
                              hipStream_t stream) {
  (void)in_sizes; (void)n_in; (void)out_size; (void)ws_size;
  const float* x      = (const float*)d_in[0];
  const float* prev   = (const float*)d_in[1];
  const float* W_in   = (const float*)d_in[2];
  const float* W_x    = (const float*)d_in[3];
  const float* W_s    = (const float*)d_in[4];
  const float* W_out  = (const float*)d_in[5];
  const float* W_gx   = (const float*)d_in[6];
  const float* b_gx   = (const float*)d_in[7];
  const float* W_gs   = (const float*)d_in[8];
  const float* b_gs   = (const float*)d_in[9];
  const float* W_dc   = (const float*)d_in[10];
  const float* b_dc   = (const float*)d_in[11];
  const float* W_pp   = (const float*)d_in[12];
  const float* b_pp   = (const float*)d_in[13];
  const float* W_pg   = (const float*)d_in[14];
  const float* b_pg   = (const float*)d_in[15];

  char* ws = (char*)d_ws;
  short* Y    = (short*)(ws + OFF_Y);
  short* H    = (short*)(ws + OFF_Y);     // aliases Y (dead after elem1)
  short* S    = (short*)(ws + OFF_S);
  short* G    = (short*)(ws + OFF_G);
  short* wcat = (short*)(ws + OFF_WCAT);
  short* wpp  = (short*)(ws + OFF_WPP);
  short* wout = (short*)(ws + OFF_WOUT);
  float* vecs = (float*)(ws + OFF_VEC);
  float* out  = (float*)d_out;

  prep_w_k<<<4352, 256, 0, stream>>>(W_in, W_x, W_gx, W_dc, W_pp, W_out, wcat, wpp, wout);
  state_k<<<160, 256, 0, stream>>>(prev, W_s, W_dc, b_dc, W_pp, b_pp, W_pg, b_pg, W_gs, b_gs, vecs);
  gemm1_k<<<768, 256, 0, stream>>>(x, wcat, Y);
  elem1_k<<<2048, 256, 0, stream>>>(Y, prev, b_gx, vecs, S, G);
  gemm2h_k<<<256, 256, 0, stream>>>(S, G, wpp, vecs, H, out);
  gemm3_k<<<1024, 256, 0, stream>>>(H, wout, out);
}

// Round 5
// 116.791 us; speedup vs baseline: 1.4743x; 1.0074x over previous
//
#include <hip/hip_runtime.h>
#include <hip/hip_bf16.h>
#include <math.h>

// ---------------------------------------------------------------------------
// GatedTinyMambaLayer: B=8, T=2048, DM=1024, DS=256
// s_prev = broadcast(prev_state) -> all s_prev-only terms are per-batch
// [8,256] precomputes. Heavy work = 3 GEMMs (m97-style: 128x128 tile, BK=32,
// global_load_lds width 16, dbuf LDS, 1 barrier/K-step).
// gemm1 stages A as f32 via global_load_lds (granule-swizzled source) and
// converts f32->bf16 at fragment-read time -> no separate cvt_x pass.
// ---------------------------------------------------------------------------

typedef __attribute__((ext_vector_type(4)))  float f32x4;
typedef __attribute__((ext_vector_type(8)))  short bf16x8;

#define DEV static __device__ __forceinline__

DEV float bf2f(short u) {
  union { float f; unsigned i; } v; v.i = ((unsigned)(unsigned short)u) << 16; return v.f;
}
DEV short f2bf(float f) {  // round-to-nearest-even
  union { float f; unsigned i; } v; v.f = f;
  unsigned x = v.i;
  return (short)((x + 0x7fffu + ((x >> 16) & 1u)) >> 16);
}
DEV unsigned pk_bf16(float lo, float hi) {  // -> v_cvt_pk_bf16_f32
  __hip_bfloat162 h = __float22bfloat162_rn(make_float2(lo, hi));
  return *(unsigned*)&h;
}
DEV float sigmoidf_(float x) { return 1.f / (1.f + expf(-x)); }

DEV void gl16(const void* g, void* l) {
  __builtin_amdgcn_global_load_lds(
      (const __attribute__((address_space(1))) void*)(g),
      (__attribute__((address_space(3))) void*)(l), 16, 0, 0);
}

// stage one 128x32 bf16 subtile pair into linear LDS [128][32] via gload_lds
DEV void stage_tile(const short* gA, const short* gB, short* As, short* Bs,
                    int lda, int ldb, int w, int lane) {
  const int rsub = lane >> 2, kc = (lane & 3) * 8;
#pragma unroll
  for (int j = 0; j < 2; ++j) {
    const int seg = w * 2 + j;           // 0..7, 16 rows each
    const int r = seg * 16 + rsub;
    gl16(gA + (size_t)r * lda + kc, As + seg * 512);
    gl16(gB + (size_t)r * ldb + kc, Bs + seg * 512);
  }
}

DEV void kstep(const short* Asb, const short* Bsb, int wr, int wc, int arow, int ag,
               f32x4 (&acc)[4][4]) {
  bf16x8 af[4], bfv[4];
#pragma unroll
  for (int mi = 0; mi < 4; ++mi)
    af[mi] = *(const bf16x8*)(Asb + (wr * 64 + mi * 16 + arow) * 32 + ag * 8);
#pragma unroll
  for (int ni = 0; ni < 4; ++ni)
    bfv[ni] = *(const bf16x8*)(Bsb + (wc * 64 + ni * 16 + arow) * 32 + ag * 8);
#pragma unroll
  for (int mi = 0; mi < 4; ++mi)
#pragma unroll
    for (int ni = 0; ni < 4; ++ni)
      acc[mi][ni] = __builtin_amdgcn_mfma_f32_16x16x32_bf16(af[mi], bfv[ni], acc[mi][ni], 0, 0, 0);
}

// ---- workspace layout (bytes) ---------------------------------------------
static const size_t OFF_Y    = 0;                   // bf16 [16384][768] = 24 MiB; H aliases after elem1
static const size_t OFF_S    = 25165824;            // bf16 [16384][256]
static const size_t OFF_G    = OFF_S + 8388608;     // bf16 [16384][256]
static const size_t OFF_WCAT = OFF_S + 33554432;    // bf16 [768][1024]
static const size_t OFF_WPP  = OFF_WCAT + 1572864;  // bf16 [256][256]  (W_pp[:, :256])
static const size_t OFF_WOUT = OFF_WPP + 131072;    // bf16 [1024][256]
static const size_t OFF_VEC  = OFF_WOUT + 524288;   // f32 [5][2048]: sdc,sws,spp,pstr,gst

// ---------------------------------------------------------------------------
__global__ __launch_bounds__(256, 1) void prep_w_k(const float* __restrict__ W_in,
                                                   const float* __restrict__ W_x,
                                                   const float* __restrict__ W_gx,
                                                   const float* __restrict__ W_dc,
                                                   const float* __restrict__ W_pp,
                                                   const float* __restrict__ W_out,
                                                   short* __restrict__ wcat,
                                                   short* __restrict__ wpp,
                                                   short* __restrict__ wout) {
  const int idx = (int)blockIdx.x * 256 + (int)threadIdx.x;
  const int N_WCAT = 768 * 1024, N_WPP = 256 * 256;
  if (idx < N_WCAT) {
    const int r = idx >> 10, k = idx & 1023;
    float v;
    if (r < 256)      v = W_in[r * 1024 + k] + W_x[r * 1024 + k];
    else if (r < 512) v = W_gx[(r - 256) * 1024 + k];
    else              v = W_dc[(r - 512) * 1280 + k];
    wcat[idx] = f2bf(v);
  } else if (idx < N_WCAT + N_WPP) {
    const int j = idx - N_WCAT, o = j >> 8, k = j & 255;
    wpp[j] = f2bf(W_pp[o * 512 + k]);          // W_pp[:, :256] (s_pred part)
  } else {
    const int j = idx - N_WCAT - N_WPP, o = j >> 8, k = j & 255;
    wout[j] = f2bf(W_out[o * 256 + k]);
  }
}

// ---------------------------------------------------------------------------
// per-batch state GEMVs, coalesced: lanes span K (float4 each), butterfly reduce.
__global__ __launch_bounds__(256, 1) void state_k(const float* __restrict__ prev,
                                                  const float* __restrict__ Ws,
                                                  const float* __restrict__ Wdc,
                                                  const float* __restrict__ bdc,
                                                  const float* __restrict__ Wpp,
                                                  const float* __restrict__ bpp,
                                                  const float* __restrict__ Wpg,
                                                  const float* __restrict__ bpg,
                                                  const float* __restrict__ Wgs,
                                                  const float* __restrict__ bgs,
                                                  float* __restrict__ vecs) {
  const int bid = (int)blockIdx.x;
  const int b = bid / 20, rem = bid % 20, m = rem >> 2, oq = rem & 3;
  const int tid = (int)threadIdx.x, lane = tid & 63, w = tid >> 6;
  const float4 sv = *(const float4*)(prev + b * 256 + lane * 4);
  const float* Wb; const float* bias; int stride, off;
  if (m == 0)      { Wb = Wdc; stride = 1280; off = 1024; bias = bdc; }
  else if (m == 1) { Wb = Ws;  stride = 256;  off = 0;    bias = nullptr; }
  else if (m == 2) { Wb = Wpp; stride = 512;  off = 256;  bias = bpp; }
  else if (m == 3) { Wb = Wpg; stride = 256;  off = 0;    bias = bpg; }
  else             { Wb = Wgs; stride = 256;  off = 0;    bias = bgs; }
  const int o0 = oq * 64 + w * 16;
#pragma unroll 4
  for (int i = 0; i < 16; ++i) {
    const int o = o0 + i;
    const float4 wv = *(const float4*)(Wb + (size_t)o * stride + off + lane * 4);
    float p = wv.x * sv.x + wv.y * sv.y + wv.z * sv.z + wv.w * sv.w;
#pragma unroll
    for (int d = 32; d >= 1; d >>= 1) p += __shfl_xor(p, d, 64);
    if (lane == 0) {
      float r = (m == 1) ? 0.5f * p : p + bias[o];
      if (m >= 3) r = sigmoidf_(r);
      vecs[m * 2048 + b * 256 + o] = r;
    }
  }
}

// ---------------------------------------------------------------------------
// GEMM1: Y[16384][768] bf16 = x(f32) @ wcat^T.  K=1024 -> 32 k-steps.
// A staged as f32 via global_load_lds, 16B-granule-swizzled on the GLOBAL
// source (g' = g ^ (row&7), involution) and un-swizzled on the LDS read ->
// conflict-free fragment reads. f32->bf16 cvt at fragment-read (cvt_pk).
// B (bf16) staged linearly via global_load_lds.
__global__ __launch_bounds__(256) void gemm1_k(const float* __restrict__ X,
                                               const short* __restrict__ Bm,
                                               short* __restrict__ Y) {
  __shared__ float Af[2][4096];   // [128][32] f32, granule-swizzled
  __shared__ short Bs[2][4096];   // [128][32] bf16 linear
  const int tid = (int)threadIdx.x, lane = tid & 63, w = tid >> 6;
  const int wr = w >> 1, wc = w & 1;
  int bid = (int)blockIdx.x;
  bid = (bid & 7) * 96 + (bid >> 3);           // XCD swizzle (768 % 8 == 0)
  const int m0 = (bid / 6) * 128, n0 = (bid % 6) * 128;
  const short* gB = Bm + (size_t)n0 * 1024;

  // A staging: seg s = w*4+j covers rows s*8..s*8+7. lane: r=lane>>3, g=lane&7.
  // source granule pre-swizzled: g' = g ^ r  (read side XORs the same).
  const int ar = lane >> 3, agr = (lane & 7) ^ ar;
  const float* gA[4];
  float* lA[4];
#pragma unroll
  for (int j = 0; j < 4; ++j) {
    const int seg = w * 4 + j;
    gA[j] = X + (size_t)(m0 + seg * 8 + ar) * 1024 + agr * 4;
    lA[j] = (float*)Af + seg * 256;   // + buf*4096
  }
  // B staging (linear)
  const int rsub = lane >> 2, kc = (lane & 3) * 8;

  f32x4 acc[4][4];
#pragma unroll
  for (int mi = 0; mi < 4; ++mi)
#pragma unroll
    for (int ni = 0; ni < 4; ++ni)
#pragma unroll
      for (int r = 0; r < 4; ++r) acc[mi][ni][r] = 0.f;

  // prologue: tile 0
#pragma unroll
  for (int j = 0; j < 4; ++j) gl16(gA[j], lA[j]);
#pragma unroll
  for (int j = 0; j < 2; ++j) {
    const int rB = (w * 2 + j) * 16 + rsub;
    gl16(gB + (size_t)rB * 1024 + kc, Bs[0] + (w * 2 + j) * 512);
  }
  __syncthreads();

  const int arow = lane & 15, ag = lane >> 4, r7 = arow & 7;
#pragma unroll 1
  for (int t = 0; t < 32; ++t) {
    const int cur = t & 1, nxt = cur ^ 1;
    if (t < 31) {
#pragma unroll
      for (int j = 0; j < 4; ++j) gl16(gA[j] + (t + 1) * 32, lA[j] + nxt * 4096);
#pragma unroll
      for (int j = 0; j < 2; ++j) {
        const int rB = (w * 2 + j) * 16 + rsub;
        gl16(gB + (size_t)rB * 1024 + (t + 1) * 32 + kc, Bs[nxt] + (w * 2 + j) * 512);
      }
    }
    {  // kstep with f32 A-frag read + cvt_pk
      const float* Afb = Af[cur];
      const short* Bsb = Bs[cur];
      bf16x8 af[4], bfv[4];
#pragma unroll
      for (int mi = 0; mi < 4; ++mi) {
        const int row = wr * 64 + mi * 16 + arow;   // row&7 == r7
        const f32x4 lo = *(const f32x4*)(Afb + row * 32 + (((ag * 2)     ^ r7) << 2));
        const f32x4 hi = *(const f32x4*)(Afb + row * 32 + (((ag * 2 + 1) ^ r7) << 2));
        uint4 pk;
        pk.x = pk_bf16(lo[0], lo[1]); pk.y = pk_bf16(lo[2], lo[3]);
        pk.z = pk_bf16(hi[0], hi[1]); pk.w = pk_bf16(hi[2], hi[3]);
        af[mi] = *(bf16x8*)&pk;
      }
#pragma unroll
      for (int ni = 0; ni < 4; ++ni)
        bfv[ni] = *(const bf16x8*)(Bsb + (wc * 64 + ni * 16 + arow) * 32 + ag * 8);
#pragma unroll
      for (int mi = 0; mi < 4; ++mi)
#pragma unroll
        for (int ni = 0; ni < 4; ++ni)
          acc[mi][ni] = __builtin_amdgcn_mfma_f32_16x16x32_bf16(af[mi], bfv[ni], acc[mi][ni], 0, 0, 0);
    }
    __syncthreads();
  }
#pragma unroll
  for (int mi = 0; mi < 4; ++mi)
#pragma unroll
    for (int ni = 0; ni < 4; ++ni) {
      const int col = n0 + wc * 64 + ni * 16 + (lane & 15);
#pragma unroll
      for (int r = 0; r < 4; ++r) {
        const int row = m0 + wr * 64 + mi * 16 + (lane >> 4) * 4 + r;
        Y[(size_t)row * 768 + col] = f2bf(acc[mi][ni][r]);
      }
    }
}

// ---------------------------------------------------------------------------
// elementwise 1: Y -> s_pred (S, bf16), gate_in (G, bf16)
__global__ __launch_bounds__(256, 1) void elem1_k(const short* __restrict__ Y,
                                                  const float* __restrict__ prev,
                                                  const float* __restrict__ bgx,
                                                  const float* __restrict__ vecs,
                                                  short* __restrict__ S,
                                                  short* __restrict__ G) {
  const int t = (int)blockIdx.x * 256 + (int)threadIdx.x;  // 524288 total
  const int row = t >> 5, gi = t & 31, j0 = gi * 8;
  const int b = row >> 11;
  const short* yr = Y + (size_t)row * 768;
  const bf16x8 yix = *(const bf16x8*)(yr + j0);
  const bf16x8 ygx = *(const bf16x8*)(yr + 256 + j0);
  const bf16x8 ydc = *(const bf16x8*)(yr + 512 + j0);
  bf16x8 so, go;
#pragma unroll
  for (int j = 0; j < 8; ++j) {
    const int c = b * 256 + j0 + j;
    const float dcl = bf2f(ydc[j]) + vecs[0 * 2048 + c];
    const float dec = expf(-0.05f * sigmoidf_(dcl));
    const float sp = prev[c] * dec + bf2f(yix[j]) + vecs[1 * 2048 + c];
    const float g = sigmoidf_(bf2f(ygx[j]) + bgx[j0 + j]);
    so[j] = f2bf(sp); go[j] = f2bf(g);
  }
  *(bf16x8*)(S + (size_t)row * 256 + j0) = so;
  *(bf16x8*)(G + (size_t)row * 256 + j0) = go;
}

// ---------------------------------------------------------------------------
// GEMM2 + elementwise: P = S @ wpp^T; h = (S + pstr*tanh(P+spp)) * G * gst
__global__ __launch_bounds__(256) void gemm2h_k(const short* __restrict__ S,
                                                const short* __restrict__ G,
                                                const short* __restrict__ Wpp,
                                                const float* __restrict__ vecs,
                                                short* __restrict__ H,
                                                float* __restrict__ out) {
  __shared__ short As[2][4096];
  __shared__ short Bs[2][4096];
  const int tid = (int)threadIdx.x, lane = tid & 63, w = tid >> 6;
  const int wr = w >> 1, wc = w & 1;
  int bid = (int)blockIdx.x;
  bid = (bid & 7) * 32 + (bid >> 3);           // 256 % 8 == 0
  const int m0 = (bid >> 1) * 128, n0 = (bid & 1) * 128;
  const int b = m0 >> 11;
  const short* gA = S + (size_t)m0 * 256;
  const short* gB = Wpp + (size_t)n0 * 256;

  f32x4 acc[4][4];
#pragma unroll
  for (int mi = 0; mi < 4; ++mi)
#pragma unroll
    for (int ni = 0; ni < 4; ++ni)
#pragma unroll
      for (int r = 0; r < 4; ++r) acc[mi][ni][r] = 0.f;

  stage_tile(gA, gB, As[0], Bs[0], 256, 256, w, lane);
  __syncthreads();
  const int arow = lane & 15, ag = lane >> 4;
#pragma unroll 1
  for (int t = 0; t < 8; ++t) {
    if (t < 7)
      stage_tile(gA + (t + 1) * 32, gB + (t + 1) * 32,
                 As[(t + 1) & 1], Bs[(t + 1) & 1], 256, 256, w, lane);
    kstep(As[t & 1], Bs[t & 1], wr, wc, arow, ag, acc);
    __syncthreads();
  }
#pragma unroll
  for (int mi = 0; mi < 4; ++mi)
#pragma unroll
    for (int ni = 0; ni < 4; ++ni) {
      const int col = n0 + wc * 64 + ni * 16 + (lane & 15);
      const float spp  = vecs[2 * 2048 + b * 256 + col];
      const float pstr = vecs[3 * 2048 + b * 256 + col];
      const float gst  = vecs[4 * 2048 + b * 256 + col];
#pragma unroll
      for (int r = 0; r < 4; ++r) {
        const int row = m0 + wr * 64 + mi * 16 + (lane >> 4) * 4 + r;
        const float pv = tanhf(acc[mi][ni][r] + spp);
        const float sp = bf2f(S[(size_t)row * 256 + col]);
        const float h = (sp + pstr * pv) * bf2f(G[(size_t)row * 256 + col]) * gst;
        H[(size_t)row * 256 + col] = f2bf(h);
        if ((row & 2047) == 2047) out[16777216 + b * 256 + col] = h;
      }
    }
}

// ---------------------------------------------------------------------------
// GEMM3: out[16384][1024] f32 = H @ wout^T. K=256 -> 8 k-steps.
__global__ __launch_bounds__(256) void gemm3_k(const short* __restrict__ H,
                                               const short* __restrict__ Wout,
                                               float* __restrict__ out) {
  __shared__ short As[2][4096];
  __shared__ short Bs[2][4096];
  const int tid = (int)threadIdx.x, lane = tid & 63, w = tid >> 6;
  const int wr = w >> 1, wc = w & 1;
  int bid = (int)blockIdx.x;
  bid = (bid & 7) * 128 + (bid >> 3);          // 1024 % 8 == 0
  const int m0 = (bid >> 3) * 128, n0 = (bid & 7) * 128;
  const short* gA = H + (size_t)m0 * 256;
  const short* gB = Wout + (size_t)n0 * 256;

  f32x4 acc[4][4];
#pragma unroll
  for (int mi = 0; mi < 4; ++mi)
#pragma unroll
    for (int ni = 0; ni < 4; ++ni)
#pragma unroll
      for (int r = 0; r < 4; ++r) acc[mi][ni][r] = 0.f;

  stage_tile(gA, gB, As[0], Bs[0], 256, 256, w, lane);
  __syncthreads();
  const int arow = lane & 15, ag = lane >> 4;
#pragma unroll 1
  for (int t = 0; t < 8; ++t) {
    if (t < 7)
      stage_tile(gA + (t + 1) * 32, gB + (t + 1) * 32,
                 As[(t + 1) & 1], Bs[(t + 1) & 1], 256, 256, w, lane);
    kstep(As[t & 1], Bs[t & 1], wr, wc, arow, ag, acc);
    __syncthreads();
  }
#pragma unroll
  for (int mi = 0; mi < 4; ++mi)
#pragma unroll
    for (int ni = 0; ni < 4; ++ni) {
      const int col = n0 + wc * 64 + ni * 16 + (lane & 15);
#pragma unroll
      for (int r = 0; r < 4; ++r) {
        const int row = m0 + wr * 64 + mi * 16 + (lane >> 4) * 4 + r;
        out[(size_t)row * 1024 + col] = acc[mi][ni][r];
      }
    }
}

// ---------------------------------------------------------------------------
extern "C" void kernel_launch(void* const* d_in, const int* in_sizes, int n_in,
                              void* d_out, int out_size, void* d_ws, size_t ws_size,
                              hipStream_t stream) {
  (void)in_sizes; (void)n_in; (void)out_size; (void)ws_size;
  const float* x      = (const float*)d_in[0];
  const float* prev   = (const float*)d_in[1];
  const float* W_in   = (const float*)d_in[2];
  const float* W_x    = (const float*)d_in[3];
  const float* W_s    = (const float*)d_in[4];
  const float* W_out  = (const float*)d_in[5];
  const float* W_gx   = (const float*)d_in[6];
  const float* b_gx   = (const float*)d_in[7];
  const float* W_gs   = (const float*)d_in[8];
  const float* b_gs   = (const float*)d_in[9];
  const float* W_dc   = (const float*)d_in[10];
  const float* b_dc   = (const float*)d_in[11];
  const float* W_pp   = (const float*)d_in[12];
  const float* b_pp   = (const float*)d_in[13];
  const float* W_pg   = (const float*)d_in[14];
  const float* b_pg   = (const float*)d_in[15];

  char* ws = (char*)d_ws;
  short* Y    = (short*)(ws + OFF_Y);
  short* H    = (short*)(ws + OFF_Y);     // aliases Y (dead after elem1)
  short* S    = (short*)(ws + OFF_S);
  short* G    = (short*)(ws + OFF_G);
  short* wcat = (short*)(ws + OFF_WCAT);
  short* wpp  = (short*)(ws + OFF_WPP);
  short* wout = (short*)(ws + OFF_WOUT);
  float* vecs = (float*)(ws + OFF_VEC);
  float* out  = (float*)d_out;

  prep_w_k<<<4352, 256, 0, stream>>>(W_in, W_x, W_gx, W_dc, W_pp, W_out, wcat, wpp, wout);
  state_k<<<160, 256, 0, stream>>>(prev, W_s, W_dc, b_dc, W_pp, b_pp, W_pg, b_pg, W_gs, b_gs, vecs);
  gemm1_k<<<768, 256, 0, stream>>>(x, wcat, Y);
  elem1_k<<<2048, 256, 0, stream>>>(Y, prev, b_gx, vecs, S, G);
  gemm2h_k<<<256, 256, 0, stream>>>(S, G, wpp, vecs, H, out);
  gemm3_k<<<1024, 256, 0, stream>>>(H, wout, out);
}